// Round 3
// baseline (406.952 us; speedup 1.0000x reference)
//
#include <hip/hip_runtime.h>
#include <stdint.h>

// MRICls fused kernel for MI355X (gfx950) — round 3.
// feat = [F0*g, F1*g, S0*g, S1*g] (464) -> 64 -> 32 -> 2 -> softmax, B=131072.
// g = sigmoid(0.25*(F0+F1)*(S0+S1)) elementwise in j.
//
// Fully-fused register path for layer 1: K is PERMUTED as
//   k' = 32t + 8h + e  <->  (segment q = h, j = 8t + e),  j in [0,120) (116 real + 4 pad)
// so MFMA A-lane (ml, h) builds its 8-elem fragment from ITS OWN row's segment h at
// j = 8t..8t+7: load own f4x2 + partner-segment f4x2 (L1-hit), u = own+pair,
// v = shfl_xor(u,32) (F-sum <-> S-sum), g = sigmoid(0.25*u*v), frag = fp16(own*g).
// No A-tile in LDS, no gate staging, no K-loop barriers; each HBM byte read once.
// W1 is prepped into the SAME permuted fragment-direct fp16 layout in ws (L2-hot).

typedef float    f4    __attribute__((ext_vector_type(4)));
typedef float    f32x4 __attribute__((ext_vector_type(4)));
typedef _Float16 h8    __attribute__((ext_vector_type(8)));

#define NSTEP 15   // K' = 480 = 15*32

__global__ void prep_w1(const float* __restrict__ W1, _Float16* __restrict__ Wsp) {
  const int e  = blockIdx.x * 256 + threadIdx.x;   // 0..30719
  const int t  = e >> 11;
  const int r  = e & 2047;
  const int n  = r & 63;
  const int kk = r >> 6;
  const int q  = kk >> 3;
  const int j  = 8 * t + (kk & 7);
  const float v = (j < 116) ? W1[(116 * q + j) * 64 + n] : 0.f;
  Wsp[t * 2048 + n * 32 + kk] = (_Float16)v;
}

__global__ __launch_bounds__(256, 4) void mricls_main(
    const float* __restrict__ F, const float* __restrict__ S,
    const float* __restrict__ b1, const float* __restrict__ W2,
    const float* __restrict__ b2, const float* __restrict__ W3,
    const float* __restrict__ b3, const _Float16* __restrict__ Wsp,
    float* __restrict__ out) {
  __shared__ __align__(16) float h1s[64][68];
  __shared__ __align__(16) float W2s[64][32];
  __shared__ __align__(16) float W3s[32][2];
  __shared__ __align__(16) float b1s[64];
  __shared__ __align__(16) float b2s[32];
  __shared__ float b3s[2];

  const int tid = threadIdx.x;
  const int l   = tid & 63;
  const int w   = tid >> 6;
  const int ml  = l & 15;
  const int h   = l >> 4;

  {
    const f4* W2v = (const f4*)W2;
    f4* W2sv = (f4*)W2s;
#pragma unroll
    for (int i = 0; i < 2; ++i) W2sv[tid + 256 * i] = W2v[tid + 256 * i];
    if (tid < 16) ((f4*)W3s)[tid] = ((const f4*)W3)[tid];
    if (tid < 16) ((f4*)b1s)[tid] = ((const f4*)b1)[tid];
    if (tid < 8)  ((f4*)b2s)[tid] = ((const f4*)b2)[tid];
    if (tid < 2)  b3s[tid] = b3[tid];
  }

  const long row = (long)blockIdx.x * 64 + w * 16 + ml;
  const float* arr   = (h < 2) ? F : S;
  const float* base  = arr + row * 232 + ((h & 1) ? 116 : 0);
  const float* pbase = arr + row * 232 + ((h & 1) ? 0 : 116);
  const _Float16* Bb = Wsp + ml * 32 + 8 * h;

  f32x4 acc[4];
#pragma unroll
  for (int nt = 0; nt < 4; ++nt) acc[nt] = (f32x4){0.f, 0.f, 0.f, 0.f};

#pragma unroll
  for (int t = 0; t < NSTEP; ++t) {
    const f4 x0 = *(const f4*)(base  + 8 * t);
    const f4 p0 = *(const f4*)(pbase + 8 * t);
    f4 x1, p1;
    if (t < NSTEP - 1) {
      x1 = *(const f4*)(base  + 8 * t + 4);
      p1 = *(const f4*)(pbase + 8 * t + 4);
    } else {
      x1 = (f4){0.f, 0.f, 0.f, 0.f};
      p1 = (f4){0.f, 0.f, 0.f, 0.f};
    }
    h8 a;
#pragma unroll
    for (int e = 0; e < 4; ++e) {
      const float u0 = x0[e] + p0[e];
      const float u1 = x1[e] + p1[e];
      const float v0 = __shfl_xor(u0, 32);
      const float v1 = __shfl_xor(u1, 32);
      const float g0 = 1.f / (1.f + __expf(-0.25f * u0 * v0));
      const float g1 = 1.f / (1.f + __expf(-0.25f * u1 * v1));
      a[e]     = (_Float16)(x0[e] * g0);
      a[e + 4] = (_Float16)(x1[e] * g1);
    }
#pragma unroll
    for (int nt = 0; nt < 4; ++nt) {
      const h8 b = *(const h8*)(Bb + t * 2048 + nt * 512);
      acc[nt] = __builtin_amdgcn_mfma_f32_16x16x32_f16(a, b, acc[nt], 0, 0, 0);
    }
  }

  __syncthreads();

#pragma unroll
  for (int nt = 0; nt < 4; ++nt) {
    const int n = nt * 16 + ml;
    const float bias = b1s[n];
#pragma unroll
    for (int r = 0; r < 4; ++r) {
      const int mm = w * 16 + h * 4 + r;
      h1s[mm][n] = fmaxf(acc[nt][r] + bias, 0.f);
    }
  }
  __syncthreads();

  const int m2 = tid >> 2;
  const int q  = tid & 3;
  float acc2[8];
#pragma unroll
  for (int e = 0; e < 8; ++e) acc2[e] = b2s[q * 8 + e];
#pragma unroll 8
  for (int k = 0; k < 64; ++k) {
    const float hk = h1s[m2][k];
    const f4 w0 = *(const f4*)&W2s[k][q * 8];
    const f4 w1 = *(const f4*)&W2s[k][q * 8 + 4];
    acc2[0] = fmaf(hk, w0[0], acc2[0]);
    acc2[1] = fmaf(hk, w0[1], acc2[1]);
    acc2[2] = fmaf(hk, w0[2], acc2[2]);
    acc2[3] = fmaf(hk, w0[3], acc2[3]);
    acc2[4] = fmaf(hk, w1[0], acc2[4]);
    acc2[5] = fmaf(hk, w1[1], acc2[5]);
    acc2[6] = fmaf(hk, w1[2], acc2[6]);
    acc2[7] = fmaf(hk, w1[3], acc2[7]);
  }
  float p0 = 0.f, p1 = 0.f;
#pragma unroll
  for (int e = 0; e < 8; ++e) {
    const float hv = fmaxf(acc2[e], 0.f);
    p0 = fmaf(hv, W3s[q * 8 + e][0], p0);
    p1 = fmaf(hv, W3s[q * 8 + e][1], p1);
  }
  p0 += __shfl_xor(p0, 1); p0 += __shfl_xor(p0, 2);
  p1 += __shfl_xor(p1, 1); p1 += __shfl_xor(p1, 2);
  if (q == 0) {
    const float l0 = p0 + b3s[0], l1 = p1 + b3s[1];
    const float mx = fmaxf(l0, l1);
    const float e0 = __expf(l0 - mx), e1 = __expf(l1 - mx);
    const float inv = 1.f / (e0 + e1);
    float2 o = make_float2(e0 * inv, e1 * inv);
    *(float2*)(out + ((long)blockIdx.x * 64 + m2) * 2) = o;
  }
}

extern "C" void kernel_launch(void* const* d_in, const int* in_sizes, int n_in,
                              void* d_out, int out_size, void* d_ws, size_t ws_size,
                              hipStream_t stream) {
  const float* F  = (const float*)d_in[0];
  const float* S  = (const float*)d_in[1];
  const float* W1 = (const float*)d_in[2];
  const float* b1 = (const float*)d_in[3];
  const float* W2 = (const float*)d_in[4];
  const float* b2 = (const float*)d_in[5];
  const float* W3 = (const float*)d_in[6];
  const float* b3 = (const float*)d_in[7];
  _Float16* Wsp = (_Float16*)d_ws;   // needs 61440 B
  float* out = (float*)d_out;
  const int B = in_sizes[0] / 232;   // 131072

  prep_w1<<<dim3(120), dim3(256), 0, stream>>>(W1, Wsp);
  mricls_main<<<dim3(B / 64), dim3(256), 0, stream>>>(F, S, b1, W2, b2, W3, b3,
                                                      (const _Float16*)Wsp, out);
}

// Round 5
// 326.036 us; speedup vs baseline: 1.2482x; 1.2482x over previous
//
#include <hip/hip_runtime.h>
#include <stdint.h>

// MRICls fused kernel for MI355X (gfx950) — round 4 (resubmit; bench never ran).
// feat = [F0*g, F1*g, S0*g, S1*g] (464) -> 64 -> 32 -> 2 -> softmax, B=131072.
// g = sigmoid(0.25*(F0+F1)*(S0+S1)) elementwise in j.
//
// K-permutation (layer-1 GEMM is permutation-invariant if W1 is permuted the same):
//   k' = 32t + 8h + 2j' + s  <->  family = (h>=2 ? S : F), seg = s, j = 8t + 4*(h&1) + j'
// So MFMA A-lane (ml, h) element pairs are (seg0[j], seg1[j]) of ITS OWN row:
//   u = x0+x1 in-lane (no xor-16 shuffle), v = shfl_xor(u, 32) (F-sum <-> S-sum),
//   g = sigmoid(0.25 u v), frag = fp16(x*g).  Pad j in [116,120) only at t=14, odd h.
// Explicit software pipeline: A-loads depth 4 (rotating f4 xb[4][2], imm offsets only),
// B-loads depth 2 (h8 bq[2][4], one pointer += 4096 B/t). No LDS in the K-loop,
// no barriers, each HBM byte read once.

typedef float    f4    __attribute__((ext_vector_type(4)));
typedef float    f32x4 __attribute__((ext_vector_type(4)));
typedef _Float16 h8    __attribute__((ext_vector_type(8)));

#define NSTEP 15   // K' = 480 = 15*32

// ---- prep: W1[116*(2*fam+s) + j][n] -> Wsp[t][n 64][kk 32] fp16, permuted K ----
__global__ void prep_w1(const float* __restrict__ W1, _Float16* __restrict__ Wsp) {
  const int e  = blockIdx.x * 256 + threadIdx.x;   // 0..30719
  const int t  = e >> 11;
  const int r  = e & 2047;
  const int n  = r & 63;
  const int kk = r >> 6;          // 0..31
  const int h  = kk >> 3;         // 0..3
  const int ee = kk & 7;
  const int s  = ee & 1;
  const int jp = ee >> 1;         // 0..3
  const int fam = h >> 1;         // 0 = F, 1 = S
  const int j  = 8 * t + 4 * (h & 1) + jp;
  const int ko = 232 * fam + 116 * s + j;
  const float v = (j < 116) ? W1[ko * 64 + n] : 0.f;
  Wsp[t * 2048 + n * 32 + kk] = (_Float16)v;
}

__global__ __launch_bounds__(256, 4) void mricls_main(
    const float* __restrict__ F, const float* __restrict__ S,
    const float* __restrict__ b1, const float* __restrict__ W2,
    const float* __restrict__ b2, const float* __restrict__ W3,
    const float* __restrict__ b3, const _Float16* __restrict__ Wsp,
    float* __restrict__ out) {
  __shared__ __align__(16) float h1s[64][68];
  __shared__ __align__(16) float W2s[64][32];
  __shared__ __align__(16) float W3s[32][2];
  __shared__ __align__(16) float b1s[64];
  __shared__ __align__(16) float b2s[32];
  __shared__ float b3s[2];

  const int tid = threadIdx.x;
  const int l   = tid & 63;
  const int w   = tid >> 6;     // wave 0..3 -> rows w*16..w*16+15
  const int ml  = l & 15;       // A row / B col
  const int h   = l >> 4;       // k-group: 0,1 = F-pairs, 2,3 = S-pairs

  // ---- small-weight staging (visibility covered by post-K-loop barrier) ----
  {
    const f4* W2v = (const f4*)W2;
    f4* W2sv = (f4*)W2s;
#pragma unroll
    for (int i = 0; i < 2; ++i) W2sv[tid + 256 * i] = W2v[tid + 256 * i];
    if (tid < 16) ((f4*)W3s)[tid] = ((const f4*)W3)[tid];
    if (tid < 16) ((f4*)b1s)[tid] = ((const f4*)b1)[tid];
    if (tid < 8)  ((f4*)b2s)[tid] = ((const f4*)b2)[tid];
    if (tid < 2)  b3s[tid] = b3[tid];
  }

  // ---- per-lane bases (all K-loop loads use imm offsets off these) ----
  const long row = (long)blockIdx.x * 64 + w * 16 + ml;
  const float* arr = (h < 2) ? F : S;
  const float* bp  = arr + row * 232 + 4 * (h & 1);          // x0 @ +8t, x1 @ +8t+116
  const float* bpt = arr + row * 232 + ((h & 1) ? 0 : 112);  // safe t=14 base (odd h: dummy)
  const char*  bptr = (const char*)Wsp + (ml * 64 + h * 16); // B: += 4096/t, imm nt*1024

  f32x4 acc[4];
#pragma unroll
  for (int nt = 0; nt < 4; ++nt) acc[nt] = (f32x4){0.f, 0.f, 0.f, 0.f};

  // ---- pipeline prologue: A depth 4, B depth 2 ----
  f4 xb[4][2];
#pragma unroll
  for (int t = 0; t < 4; ++t) {
    xb[t][0] = *(const f4*)(bp + 8 * t);
    xb[t][1] = *(const f4*)(bp + 8 * t + 116);
  }
  h8 bq[2][4];
#pragma unroll
  for (int nt = 0; nt < 4; ++nt) bq[0][nt] = *(const h8*)(bptr + nt * 1024);
#pragma unroll
  for (int nt = 0; nt < 4; ++nt) bq[1][nt] = *(const h8*)(bptr + 4096 + nt * 1024);
  bptr += 8192;   // next B target: t = 2

  // ---- fused K-loop: consume t; issue A(t+4), B(t+2). No barriers. ----
#pragma unroll
  for (int t = 0; t < NSTEP; ++t) {
    f4 cx0 = xb[t & 3][0];
    f4 cx1 = xb[t & 3][1];
    // refill A slot with step t+4 (WAR on xb keeps order; issue is early & independent)
    if (t + 4 < 14) {
      xb[t & 3][0] = *(const f4*)(bp + 8 * (t + 4));
      xb[t & 3][1] = *(const f4*)(bp + 8 * (t + 4) + 116);
    } else if (t + 4 == 14) {   // tail step: odd-h lanes read dummies (zeroed at consume)
      xb[t & 3][0] = *(const f4*)(bpt);
      xb[t & 3][1] = *(const f4*)(bpt + 116);
    }
    if (t == 14) {  // zero pad lanes (j >= 116): odd h at t=14
      const float zf = (h & 1) ? 0.f : 1.f;
#pragma unroll
      for (int e = 0; e < 4; ++e) { cx0[e] *= zf; cx1[e] *= zf; }
    }
    // gate + fragment (all in-lane except one xor-32 swap)
    h8 a;
#pragma unroll
    for (int jp = 0; jp < 4; ++jp) {
      const float u = cx0[jp] + cx1[jp];
      const float v = __shfl_xor(u, 32);           // F-sum <-> S-sum (h ^ 2)
      const float g = 1.f / (1.f + __expf(-0.25f * u * v));
      a[2 * jp]     = (_Float16)(cx0[jp] * g);
      a[2 * jp + 1] = (_Float16)(cx1[jp] * g);
    }
#pragma unroll
    for (int nt = 0; nt < 4; ++nt)
      acc[nt] = __builtin_amdgcn_mfma_f32_16x16x32_f16(a, bq[t & 1][nt], acc[nt], 0, 0, 0);
    // refill B slot with step t+2 (WAR on bq orders after the MFMA issues above)
    if (t + 2 < NSTEP) {
#pragma unroll
      for (int nt = 0; nt < 4; ++nt) bq[t & 1][nt] = *(const h8*)(bptr + nt * 1024);
      bptr += 4096;
    }
  }

  __syncthreads();

  // ---- epilogue: h1 = relu(acc + b1) -> LDS ----
#pragma unroll
  for (int nt = 0; nt < 4; ++nt) {
    const int n = nt * 16 + ml;
    const float bias = b1s[n];
#pragma unroll
    for (int r = 0; r < 4; ++r) {
      const int mm = w * 16 + h * 4 + r;  // C/D: col=lane&15, row=(lane>>4)*4+reg
      h1s[mm][n] = fmaxf(acc[nt][r] + bias, 0.f);
    }
  }
  __syncthreads();

  // ---- layers 2,3 + softmax (fp32 VALU; 4 threads per row) ----
  const int m2 = tid >> 2;  // row 0..63
  const int q  = tid & 3;   // 8 h2-outputs each
  float acc2[8];
#pragma unroll
  for (int e = 0; e < 8; ++e) acc2[e] = b2s[q * 8 + e];
#pragma unroll 8
  for (int k = 0; k < 64; ++k) {
    const float hk = h1s[m2][k];
    const f4 w0 = *(const f4*)&W2s[k][q * 8];
    const f4 w1 = *(const f4*)&W2s[k][q * 8 + 4];
    acc2[0] = fmaf(hk, w0[0], acc2[0]);
    acc2[1] = fmaf(hk, w0[1], acc2[1]);
    acc2[2] = fmaf(hk, w0[2], acc2[2]);
    acc2[3] = fmaf(hk, w0[3], acc2[3]);
    acc2[4] = fmaf(hk, w1[0], acc2[4]);
    acc2[5] = fmaf(hk, w1[1], acc2[5]);
    acc2[6] = fmaf(hk, w1[2], acc2[6]);
    acc2[7] = fmaf(hk, w1[3], acc2[7]);
  }
  float p0 = 0.f, p1 = 0.f;
#pragma unroll
  for (int e = 0; e < 8; ++e) {
    const float hv = fmaxf(acc2[e], 0.f);
    p0 = fmaf(hv, W3s[q * 8 + e][0], p0);
    p1 = fmaf(hv, W3s[q * 8 + e][1], p1);
  }
  p0 += __shfl_xor(p0, 1); p0 += __shfl_xor(p0, 2);
  p1 += __shfl_xor(p1, 1); p1 += __shfl_xor(p1, 2);
  if (q == 0) {
    const float l0 = p0 + b3s[0], l1 = p1 + b3s[1];
    const float mx = fmaxf(l0, l1);
    const float e0 = __expf(l0 - mx), e1 = __expf(l1 - mx);
    const float inv = 1.f / (e0 + e1);
    float2 o = make_float2(e0 * inv, e1 * inv);
    *(float2*)(out + ((long)blockIdx.x * 64 + m2) * 2) = o;
  }
}

extern "C" void kernel_launch(void* const* d_in, const int* in_sizes, int n_in,
                              void* d_out, int out_size, void* d_ws, size_t ws_size,
                              hipStream_t stream) {
  const float* F  = (const float*)d_in[0];
  const float* S  = (const float*)d_in[1];
  const float* W1 = (const float*)d_in[2];
  const float* b1 = (const float*)d_in[3];
  const float* W2 = (const float*)d_in[4];
  const float* b2 = (const float*)d_in[5];
  const float* W3 = (const float*)d_in[6];
  const float* b3 = (const float*)d_in[7];
  _Float16* Wsp = (_Float16*)d_ws;   // needs 61440 B
  float* out = (float*)d_out;
  const int B = in_sizes[0] / 232;   // 131072

  prep_w1<<<dim3(120), dim3(256), 0, stream>>>(W1, Wsp);
  mricls_main<<<dim3(B / 64), dim3(256), 0, stream>>>(F, S, b1, W2, b2, W3, b3,
                                                      (const _Float16*)Wsp, out);
}

// Round 6
// 299.455 us; speedup vs baseline: 1.3590x; 1.0888x over previous
//
#include <hip/hip_runtime.h>
#include <stdint.h>

// MRICls fused kernel for MI355X (gfx950) — round 6.
// feat = [F0*g, F1*g, S0*g, S1*g] (464) -> 64 -> 32 -> 2 -> softmax, B=131072.
// g = sigmoid(0.25*(F0+F1)*(S0+S1)) elementwise in j.
//
// K-permutation (unchanged from r4/r5; W1 prepped identically so GEMM invariant):
//   k' = 32t + 8h + 2jp + s <-> family=(h>=2?S:F), seg=s, j = 8t + 4*(h&1) + jp
// NEW: F/S stream via global_load_lds into PER-WAVE-PRIVATE double-buffered 4 KB
// chunks (chunk = 2 K-steps = 16 j's x 4 segs x own 16 rows). Each wave stages and
// consumes its own rows -> NO barriers in the K-loop. Counted vmcnt(12) keeps the
// next chunk's 4 gll + 8 B-loads in flight across the wait (T3/T4); issue counts
// pinned by asm volatile + sched_barrier(0) fences. B (W1 frags) double-buffered
// in regs via asm global_load_dwordx4 (L2-hot). LDS 41.6 KB -> 3 blocks/CU.

typedef float    f4    __attribute__((ext_vector_type(4)));
typedef float    f32x4 __attribute__((ext_vector_type(4)));
typedef _Float16 h8    __attribute__((ext_vector_type(8)));
typedef int      i4    __attribute__((ext_vector_type(4)));

#define NSTEP 15

// ---- prep: W1[116*(2*fam+s) + j][n] -> Wsp[t][n 64][kk 32] fp16, permuted K ----
__global__ void prep_w1(const float* __restrict__ W1, _Float16* __restrict__ Wsp) {
  const int e  = blockIdx.x * 256 + threadIdx.x;   // 0..30719
  const int t  = e >> 11;
  const int r  = e & 2047;
  const int n  = r & 63;
  const int kk = r >> 6;          // 0..31
  const int h  = kk >> 3;         // 0..3
  const int ee = kk & 7;
  const int s  = ee & 1;
  const int jp = ee >> 1;         // 0..3
  const int fam = h >> 1;         // 0 = F, 1 = S
  const int j  = 8 * t + 4 * (h & 1) + jp;
  const int ko = 232 * fam + 116 * s + j;
  const float v = (j < 116) ? W1[ko * 64 + n] : 0.f;
  Wsp[t * 2048 + n * 32 + kk] = (_Float16)v;
}

// asm B-load: 16 B global -> i4 reg, imm byte offset (<= 4095)
#define BL(dst, addr, imm)                                                  \
  asm volatile("global_load_dwordx4 %0, %1, off offset:" #imm               \
               : "=v"(dst) : "v"(addr));

__global__ __launch_bounds__(256, 3) void mricls_main(
    const float* __restrict__ F, const float* __restrict__ S,
    const float* __restrict__ b1, const float* __restrict__ W2,
    const float* __restrict__ b2, const float* __restrict__ W3,
    const float* __restrict__ b3, const _Float16* __restrict__ Wsp,
    float* __restrict__ out) {
  // Chunk buffers (32 KB; per-wave 8 KB = 2 bufs x 4 KB) overlaid with h1 (17 KB).
  __shared__ __align__(16) union {
    char  cbuf[32768];
    float h1[64][68];
  } U;
  __shared__ __align__(16) float W2s[64][32];
  __shared__ __align__(16) float W3s[32][2];
  __shared__ __align__(16) float b1s[64];
  __shared__ __align__(16) float b2s[32];
  __shared__ float b3s[2];

  const int tid = threadIdx.x;
  const int l   = tid & 63;
  const int w   = tid >> 6;     // wave 0..3 -> rows w*16..w*16+15
  const int ml  = l & 15;       // A row / B col
  const int h   = l >> 4;       // k-group: 0,1 = F-pairs, 2,3 = S-pairs

  // ---- small-weight staging (loads oldest in vmcnt order; visibility via
  //      the post-K-loop __syncthreads) ----
  {
    const f4* W2v = (const f4*)W2;
    f4* W2sv = (f4*)W2s;
#pragma unroll
    for (int i = 0; i < 2; ++i) W2sv[tid + 256 * i] = W2v[tid + 256 * i];
    if (tid < 16) ((f4*)W3s)[tid] = ((const f4*)W3)[tid];
    if (tid < 16) ((f4*)b1s)[tid] = ((const f4*)b1)[tid];
    if (tid < 8)  ((f4*)b2s)[tid] = ((const f4*)b2)[tid];
    if (tid < 2)  b3s[tid] = b3[tid];
  }

  // ---- gll source pointers: call i stages seg i for this wave's 16 rows.
  //      lane L: row = w*16 + (L>>2), 16-B piece q = L&3 (64-B coalesced granule).
  //      chunk c adds c*16 floats (baked into pointer; folds to imm offset). ----
  const long rowG = (long)blockIdx.x * 64 + w * 16 + (l >> 2);
  const float* g0 = F + rowG * 232 +   0 + (l & 3) * 4;   // F seg0
  const float* g1 = F + rowG * 232 + 116 + (l & 3) * 4;   // F seg1
  const float* g2 = S + rowG * 232 +   0 + (l & 3) * 4;   // S seg0
  const float* g3 = S + rowG * 232 + 116 + (l & 3) * 4;   // S seg1
  // chunk-7 sources (j base 112; all 4 lanes of a row read the same 16 B -> q>=1
  // units get dup data, consumed only at q<=1 where q=1 values are masked (odd h)).
  const float* g70 = F + rowG * 232 +   0 + 112;
  const float* g71 = F + rowG * 232 + 116 + 112;
  const float* g72 = S + rowG * 232 +   0 + 112;
  const float* g73 = S + rowG * 232 + 116 + 112;

  // LDS dest base for this wave (gll writes linear: base + lane*16)
  char* lds0 = U.cbuf + w * 8192;               // + buf*4096 + i*1024
  // consumer ds_read base: unit = seg*64 + ml*4 + q  (16-B units)
  const char* rbase = U.cbuf + w * 8192 + (h >> 1) * 2048 + ml * 64 + (h & 1) * 16;

  // B fragment pointer for this lane
  const char* bbase = (const char*)Wsp + ml * 64 + h * 16;  // + t*4096 + nt*1024

  f32x4 acc[4];
#pragma unroll
  for (int nt = 0; nt < 4; ++nt) acc[nt] = (f32x4){0.f, 0.f, 0.f, 0.f};

  i4 bq[2][2][4];   // [set = chunk parity][step-in-chunk][nt] — all indices literal
  const float zf = (h & 1) ? 0.f : 1.f;   // step-14 pad mask (odd h = j>=116)

  // ---- prologue: stage chunk 0 (buf 0) + B(steps 0,1) -> set 0 ----
  __builtin_amdgcn_global_load_lds(g0, lds0 +    0, 16, 0, 0);
  __builtin_amdgcn_global_load_lds(g1, lds0 + 1024, 16, 0, 0);
  __builtin_amdgcn_global_load_lds(g2, lds0 + 2048, 16, 0, 0);
  __builtin_amdgcn_global_load_lds(g3, lds0 + 3072, 16, 0, 0);
  {
    const void* be = bbase;               // step 0
    const void* bo = bbase + 4096;        // step 1
    BL(bq[0][0][0], be, 0)    BL(bq[0][0][1], be, 1024)
    BL(bq[0][0][2], be, 2048) BL(bq[0][0][3], be, 3072)
    BL(bq[0][1][0], bo, 0)    BL(bq[0][1][1], bo, 1024)
    BL(bq[0][1][2], bo, 2048) BL(bq[0][1][3], bo, 3072)
  }

#define DO_STEP(cc, tt, TAIL)                                                  \
  {                                                                            \
    const f4 x0 = *(const f4*)(rbase + ((cc)&1) * 4096 + (tt) * 32);           \
    const f4 x1 = *(const f4*)(rbase + ((cc)&1) * 4096 + (tt) * 32 + 1024);    \
    h8 a;                                                                      \
    _Pragma("unroll")                                                          \
    for (int jp = 0; jp < 4; ++jp) {                                           \
      float xe0 = x0[jp], xe1 = x1[jp];                                        \
      if (TAIL) { xe0 *= zf; xe1 *= zf; }                                      \
      const float u = xe0 + xe1;                                               \
      const float v = __shfl_xor(u, 32);                                       \
      const float g = 1.f / (1.f + __expf(-0.25f * u * v));                    \
      a[2 * jp]     = (_Float16)(xe0 * g);                                     \
      a[2 * jp + 1] = (_Float16)(xe1 * g);                                     \
    }                                                                          \
    acc[0] = __builtin_amdgcn_mfma_f32_16x16x32_f16(                           \
        a, __builtin_bit_cast(h8, bq[(cc)&1][tt][0]), acc[0], 0, 0, 0);        \
    acc[1] = __builtin_amdgcn_mfma_f32_16x16x32_f16(                           \
        a, __builtin_bit_cast(h8, bq[(cc)&1][tt][1]), acc[1], 0, 0, 0);        \
    acc[2] = __builtin_amdgcn_mfma_f32_16x16x32_f16(                           \
        a, __builtin_bit_cast(h8, bq[(cc)&1][tt][2]), acc[2], 0, 0, 0);        \
    acc[3] = __builtin_amdgcn_mfma_f32_16x16x32_f16(                           \
        a, __builtin_bit_cast(h8, bq[(cc)&1][tt][3]), acc[3], 0, 0, 0);        \
  }

  // ---- K-loop: 7 iters, 2 steps each; barrier-free, counted vmcnt ----
#pragma unroll
  for (int c = 0; c < 7; ++c) {
    char* dst = lds0 + ((c + 1) & 1) * 4096;
    if (c < 6) {
      // stage chunk c+1 (source advance baked into pointer -> imm offset)
      __builtin_amdgcn_global_load_lds(g0 + (c + 1) * 16, dst +    0, 16, 0, 0);
      __builtin_amdgcn_global_load_lds(g1 + (c + 1) * 16, dst + 1024, 16, 0, 0);
      __builtin_amdgcn_global_load_lds(g2 + (c + 1) * 16, dst + 2048, 16, 0, 0);
      __builtin_amdgcn_global_load_lds(g3 + (c + 1) * 16, dst + 3072, 16, 0, 0);
      // B for steps 2c+2, 2c+3 -> set (c+1)&1
      const void* be = bbase + (size_t)(2 * c + 2) * 4096;
      const void* bo = bbase + (size_t)(2 * c + 3) * 4096;
      if ((c + 1) & 1) {
        BL(bq[1][0][0], be, 0)    BL(bq[1][0][1], be, 1024)
        BL(bq[1][0][2], be, 2048) BL(bq[1][0][3], be, 3072)
        BL(bq[1][1][0], bo, 0)    BL(bq[1][1][1], bo, 1024)
        BL(bq[1][1][2], bo, 2048) BL(bq[1][1][3], bo, 3072)
      } else {
        BL(bq[0][0][0], be, 0)    BL(bq[0][0][1], be, 1024)
        BL(bq[0][0][2], be, 2048) BL(bq[0][0][3], be, 3072)
        BL(bq[0][1][0], bo, 0)    BL(bq[0][1][1], bo, 1024)
        BL(bq[0][1][2], bo, 2048) BL(bq[0][1][3], bo, 3072)
      }
      __builtin_amdgcn_sched_barrier(0);
      asm volatile("s_waitcnt vmcnt(12)" ::: "memory");
      __builtin_amdgcn_sched_barrier(0);
    } else {
      // stage chunk 7 (step 14 only) + B(14) -> set 1
      __builtin_amdgcn_global_load_lds(g70, dst +    0, 16, 0, 0);
      __builtin_amdgcn_global_load_lds(g71, dst + 1024, 16, 0, 0);
      __builtin_amdgcn_global_load_lds(g72, dst + 2048, 16, 0, 0);
      __builtin_amdgcn_global_load_lds(g73, dst + 3072, 16, 0, 0);
      const void* be = bbase + (size_t)14 * 4096;
      BL(bq[1][0][0], be, 0)    BL(bq[1][0][1], be, 1024)
      BL(bq[1][0][2], be, 2048) BL(bq[1][0][3], be, 3072)
      __builtin_amdgcn_sched_barrier(0);
      asm volatile("s_waitcnt vmcnt(8)" ::: "memory");
      __builtin_amdgcn_sched_barrier(0);
    }
    DO_STEP(c, 0, false)
    DO_STEP(c, 1, false)
  }
  // epilogue: chunk 7 = step 14 (buf 1, tt=0, pad-masked)
  __builtin_amdgcn_sched_barrier(0);
  asm volatile("s_waitcnt vmcnt(0)" ::: "memory");
  __builtin_amdgcn_sched_barrier(0);
  DO_STEP(7, 0, true)

  __syncthreads();  // chunk bufs dead -> h1 region live (cross-wave)

  // ---- epilogue: h1 = relu(acc + b1) -> LDS ----
#pragma unroll
  for (int nt = 0; nt < 4; ++nt) {
    const int n = nt * 16 + ml;
    const float bias = b1s[n];
#pragma unroll
    for (int r = 0; r < 4; ++r) {
      const int mm = w * 16 + h * 4 + r;  // C/D: col=lane&15, row=(lane>>4)*4+reg
      U.h1[mm][n] = fmaxf(acc[nt][r] + bias, 0.f);
    }
  }
  __syncthreads();

  // ---- layers 2,3 + softmax (fp32 VALU; 4 threads per row) ----
  const int m2 = tid >> 2;  // row 0..63
  const int q  = tid & 3;   // 8 h2-outputs each
  float acc2[8];
#pragma unroll
  for (int e = 0; e < 8; ++e) acc2[e] = b2s[q * 8 + e];
#pragma unroll 8
  for (int k = 0; k < 64; ++k) {
    const float hk = U.h1[m2][k];
    const f4 w0 = *(const f4*)&W2s[k][q * 8];
    const f4 w1 = *(const f4*)&W2s[k][q * 8 + 4];
    acc2[0] = fmaf(hk, w0[0], acc2[0]);
    acc2[1] = fmaf(hk, w0[1], acc2[1]);
    acc2[2] = fmaf(hk, w0[2], acc2[2]);
    acc2[3] = fmaf(hk, w0[3], acc2[3]);
    acc2[4] = fmaf(hk, w1[0], acc2[4]);
    acc2[5] = fmaf(hk, w1[1], acc2[5]);
    acc2[6] = fmaf(hk, w1[2], acc2[6]);
    acc2[7] = fmaf(hk, w1[3], acc2[7]);
  }
  float p0 = 0.f, p1 = 0.f;
#pragma unroll
  for (int e = 0; e < 8; ++e) {
    const float hv = fmaxf(acc2[e], 0.f);
    p0 = fmaf(hv, W3s[q * 8 + e][0], p0);
    p1 = fmaf(hv, W3s[q * 8 + e][1], p1);
  }
  p0 += __shfl_xor(p0, 1); p0 += __shfl_xor(p0, 2);
  p1 += __shfl_xor(p1, 1); p1 += __shfl_xor(p1, 2);
  if (q == 0) {
    const float l0 = p0 + b3s[0], l1 = p1 + b3s[1];
    const float mx = fmaxf(l0, l1);
    const float e0 = __expf(l0 - mx), e1 = __expf(l1 - mx);
    const float inv = 1.f / (e0 + e1);
    float2 o = make_float2(e0 * inv, e1 * inv);
    *(float2*)(out + ((long)blockIdx.x * 64 + m2) * 2) = o;
  }
}

extern "C" void kernel_launch(void* const* d_in, const int* in_sizes, int n_in,
                              void* d_out, int out_size, void* d_ws, size_t ws_size,
                              hipStream_t stream) {
  const float* F  = (const float*)d_in[0];
  const float* S  = (const float*)d_in[1];
  const float* W1 = (const float*)d_in[2];
  const float* b1 = (const float*)d_in[3];
  const float* W2 = (const float*)d_in[4];
  const float* b2 = (const float*)d_in[5];
  const float* W3 = (const float*)d_in[6];
  const float* b3 = (const float*)d_in[7];
  _Float16* Wsp = (_Float16*)d_ws;   // needs 61440 B
  float* out = (float*)d_out;
  const int B = in_sizes[0] / 232;   // 131072

  prep_w1<<<dim3(120), dim3(256), 0, stream>>>(W1, Wsp);
  mricls_main<<<dim3(B / 64), dim3(256), 0, stream>>>(F, S, b1, W2, b2, W3, b3,
                                                      (const _Float16*)Wsp, out);
}